// Round 5
// baseline (463.346 us; speedup 1.0000x reference)
//
#include <hip/hip_runtime.h>

#define B_TOT 4096
#define T_LEN 512
#define DIN   8
#define H_DIM 50

typedef __attribute__((ext_vector_type(8))) short  short8;   // 8 bf16 (4 VGPRs)
typedef __attribute__((ext_vector_type(4))) float  floatx4;  // MFMA acc

static __device__ __forceinline__ uint  asu(float f){ return __float_as_uint(f); }
static __device__ __forceinline__ float asf(uint u){ return __uint_as_float(u); }
static __device__ __forceinline__ ushort f2bf_rne(float f){
  uint u = asu(f); u += 0x7FFFu + ((u>>16)&1u); return (ushort)(u>>16);
}
static __device__ __forceinline__ float bf2f(ushort b){ return asf(((uint)b)<<16); }
// pack two floats' truncated-bf16 into one uint (a->lo16, b->hi16)
static __device__ __forceinline__ uint pack_hi(float a, float b){
  return (asu(a)>>16) | (asu(b)&0xFFFF0000u);
}
// pack the bf16-trunc of the residuals (a - trunc(a)), (b - trunc(b))
static __device__ __forceinline__ uint pack_lo(float a, float b){
  float ra = a - asf(asu(a)&0xFFFF0000u);
  float rb = b - asf(asu(b)&0xFFFF0000u);
  return (asu(ra)>>16) | (asu(rb)&0xFFFF0000u);
}
static __device__ __forceinline__ float ftanh(float v){
  float e = __expf(2.0f*v);
  return 1.0f - 2.0f*__builtin_amdgcn_rcpf(1.0f + e);
}

// Dim permutation: tile t4, D-row m=kg*4+r  <->  global dim
//   d(t4,kg,r) = 32*(t4>>1) + 4*(t4&1) + 8*kg + r
// With this mapping, the packed pair P[t4][q] (r=2q,2q+1) at lane (kg,col) is
// EXACTLY the b32 the same lane needs for next step's B-frag slot:
//   Bh0 = {P00,P01,P10,P11}, Bh1 = {P20,P21,P30,P31}   (x/zeros patched at kg>=2)
__global__ __launch_bounds__(64, 1) void rnn_regchain(
    const float* __restrict__ x, const float* __restrict__ W_ih,
    const float* __restrict__ W_hh, const float* __restrict__ b_ih,
    const float* __restrict__ b_hh, const float* __restrict__ fc_W,
    const float* __restrict__ fc_b, float* __restrict__ out)
{
  const int lane = threadIdx.x;
  const int col  = lane & 15;     // batch within block (B-frag n, A-frag m)
  const int kg   = lane >> 4;     // 0..3
  const int b0   = blockIdx.x * 16;

  // ---- W fragments (A-operand, permuted rows), hi/lo split, in VGPRs ----
  short8 Wh[4][2], Wl[4][2];
#pragma unroll
  for (int t4 = 0; t4 < 4; ++t4) {
    const int drow = 32*(t4>>1) + 4*(t4&1) + 8*(col>>2) + (col&3); // A row m=col
#pragma unroll
    for (int kh = 0; kh < 2; ++kh) {
      union { ushort u[8]; short8 v; } hu, lu;
#pragma unroll
      for (int j = 0; j < 8; ++j) {
        int k = kh*32 + kg*8 + j;
        float w = 0.f;
        if (drow < H_DIM) {
          if (k < H_DIM)            w = W_hh[drow*H_DIM + k];
          else if (k < H_DIM + DIN) w = W_ih[drow*DIN + (k - H_DIM)];
        }
        ushort h = f2bf_rne(w);
        hu.u[j] = h;
        lu.u[j] = (ushort)(asu(w - bf2f(h)) >> 16);
      }
      Wh[t4][kh] = hu.v; Wl[t4][kh] = lu.v;
    }
  }

  // bias per acc reg: D row uses kg: d = base(t4) + 8*kg + r
  floatx4 bias[4];
#pragma unroll
  for (int t4 = 0; t4 < 4; ++t4)
#pragma unroll
    for (int r = 0; r < 4; ++r) {
      int d = 32*(t4>>1) + 4*(t4&1) + 8*kg + r;
      bias[t4][r] = (d < H_DIM) ? (b_ih[d] + b_hh[d]) : 0.f;
    }

  // ---- x streaming: lane (kg=2): x[0..5]; (kg=3): x[6..7]; per own batch col
  const float*  xb  = x + (size_t)(b0 + col) * (T_LEN * DIN);
  const float4* xp4 = (const float4*)xb;                       // idx 2*t  (kg2)
  const float2* xp2 = (const float2*)(xb + ((kg == 2) ? 4 : 6)); // idx 4*t

  float4 c04 = {0,0,0,0}; float2 c02 = {0,0};
  float4 pA4 = {0,0,0,0}, pB4 = {0,0,0,0};
  float2 pA2 = {0,0}, pB2 = {0,0};
  if (kg >= 2) {
    c02 = xp2[0]; pA2 = xp2[4]; pB2 = xp2[8];
    if (kg == 2) { c04 = xp4[0]; pA4 = xp4[2]; pB4 = xp4[4]; }
  }

  // ---- recurrence state: packed tanh outputs (hi/lo), start at h0 = 0 ----
  uint Ph[4][2] = {{0,0},{0,0},{0,0},{0,0}};
  uint Pl[4][2] = {{0,0},{0,0},{0,0},{0,0}};
  short8 Bh0, Bh1, Bl0, Bl1;

  auto assemble = [&](float4 v4, float2 v2) {
    uint nxh0=0, nxh1=0, nxh2=0, nxl0=0, nxl1=0, nxl2=0;
    if (kg == 2) {
      nxh0 = pack_hi(v4.x, v4.y); nxl0 = pack_lo(v4.x, v4.y);
      nxh1 = pack_hi(v4.z, v4.w); nxl1 = pack_lo(v4.z, v4.w);
      nxh2 = pack_hi(v2.x, v2.y); nxl2 = pack_lo(v2.x, v2.y);
    } else if (kg == 3) {
      nxh0 = pack_hi(v2.x, v2.y); nxl0 = pack_lo(v2.x, v2.y);
    }
    union { uint u[4]; short8 v; } a, b, c, d;
    a.u[0]=Ph[0][0]; a.u[1]=Ph[0][1]; a.u[2]=Ph[1][0]; a.u[3]=Ph[1][1];
    c.u[0]=Pl[0][0]; c.u[1]=Pl[0][1]; c.u[2]=Pl[1][0]; c.u[3]=Pl[1][1];
    uint h0=Ph[2][0], h1=Ph[2][1], h2=Ph[3][0], h3=Ph[3][1];
    uint l0=Pl[2][0], l1=Pl[2][1], l2=Pl[3][0], l3=Pl[3][1];
    if (kg == 2) { h1=nxh0; h2=nxh1; h3=nxh2; l1=nxl0; l2=nxl1; l3=nxl2; }
    if (kg == 3) { h0=nxh0; h1=0; h2=0; h3=0; l0=nxl0; l1=0; l2=0; l3=0; }
    b.u[0]=h0; b.u[1]=h1; b.u[2]=h2; b.u[3]=h3;
    d.u[0]=l0; d.u[1]=l1; d.u[2]=l2; d.u[3]=l3;
    Bh0=a.v; Bh1=b.v; Bl0=c.v; Bl1=d.v;
  };
  assemble(c04, c02);   // frags for t=0: h=0 + x_0

  // ---- main loop: no LDS, no barriers; everything register-resident ----
  auto phase = [&](float4& p4, float2& p2, int tn) {
    float4 cv4 = p4; float2 cv2 = p2;           // x_{t+1}, loaded 2 steps ago
    if (tn > T_LEN - 1) tn = T_LEN - 1;
    if (kg >= 2) {                               // reload for t+3 (2-step lead)
      p2 = xp2[4*tn];
      if (kg == 2) p4 = xp4[2*tn];
    }
    floatx4 acc[4];
#pragma unroll
    for (int t4 = 0; t4 < 4; ++t4) {
      floatx4 a = bias[t4];
      a = __builtin_amdgcn_mfma_f32_16x16x32_bf16(Wh[t4][0], Bh0, a, 0, 0, 0);
      a = __builtin_amdgcn_mfma_f32_16x16x32_bf16(Wh[t4][1], Bh1, a, 0, 0, 0);
      a = __builtin_amdgcn_mfma_f32_16x16x32_bf16(Wl[t4][0], Bh0, a, 0, 0, 0);
      a = __builtin_amdgcn_mfma_f32_16x16x32_bf16(Wl[t4][1], Bh1, a, 0, 0, 0);
      a = __builtin_amdgcn_mfma_f32_16x16x32_bf16(Wh[t4][0], Bl0, a, 0, 0, 0);
      a = __builtin_amdgcn_mfma_f32_16x16x32_bf16(Wh[t4][1], Bl1, a, 0, 0, 0);
      acc[t4] = a;
    }
#pragma unroll
    for (int t4 = 0; t4 < 4; ++t4) {
      float t0 = ftanh(acc[t4][0]), t1 = ftanh(acc[t4][1]);
      float t2 = ftanh(acc[t4][2]), t3 = ftanh(acc[t4][3]);
      Ph[t4][0] = pack_hi(t0, t1); Pl[t4][0] = pack_lo(t0, t1);
      Ph[t4][1] = pack_hi(t2, t3); Pl[t4][1] = pack_lo(t2, t3);
    }
    assemble(cv4, cv2);                          // frags for t+1
  };

  for (int it = 0; it < T_LEN; it += 2) {
    phase(pA4, pA2, it + 3);
    phase(pB4, pB2, it + 4);
  }
  // Ph/Pl now hold h_T (packed, per-lane dims {8kg..8kg+7} ∪ {32+8kg..32+8kg+7})

  // ---- fc readout ----
  float fs = 0.f;
#pragma unroll
  for (int i = 0; i < 8; ++i) {                  // dims 8kg+i  (< 32, all real)
    int d  = 8*kg + i;
    uint ph = Ph[i>>2][(i>>1)&1], pl = Pl[i>>2][(i>>1)&1];
    float hv = (i & 1) ? (asf(ph & 0xFFFF0000u) + asf(pl & 0xFFFF0000u))
                       : (asf(ph << 16)         + asf(pl << 16));
    fs += fc_W[d] * hv;
  }
#pragma unroll
  for (int i = 0; i < 8; ++i) {                  // dims 32+8kg+i (mask >= 50)
    int d = 32 + 8*kg + i;
    if (d < H_DIM) {
      uint ph = Ph[2+(i>>2)][(i>>1)&1], pl = Pl[2+(i>>2)][(i>>1)&1];
      float hv = (i & 1) ? (asf(ph & 0xFFFF0000u) + asf(pl & 0xFFFF0000u))
                         : (asf(ph << 16)         + asf(pl << 16));
      fs += fc_W[d] * hv;
    }
  }
  fs += __shfl_xor(fs, 16);
  fs += __shfl_xor(fs, 32);
  if (kg == 0) out[b0 + col] = fs + fc_b[0];
}

extern "C" void kernel_launch(void* const* d_in, const int* in_sizes, int n_in,
                              void* d_out, int out_size, void* d_ws, size_t ws_size,
                              hipStream_t stream) {
  const float* x    = (const float*)d_in[0];
  const float* W_ih = (const float*)d_in[1];
  const float* W_hh = (const float*)d_in[2];
  const float* b_ih = (const float*)d_in[3];
  const float* b_hh = (const float*)d_in[4];
  const float* fc_W = (const float*)d_in[5];
  const float* fc_b = (const float*)d_in[6];
  rnn_regchain<<<dim3(B_TOT / 16), dim3(64), 0, stream>>>(
      x, W_ih, W_hh, b_ih, b_hh, fc_W, fc_b, (float*)d_out);
}

// Round 6
// 463.164 us; speedup vs baseline: 1.0004x; 1.0004x over previous
//
#include <hip/hip_runtime.h>

#define B_TOT 4096
#define T_LEN 512
#define DIN   8
#define H_DIM 50

typedef __attribute__((ext_vector_type(8))) short  short8;   // 8 bf16 (4 VGPRs)
typedef __attribute__((ext_vector_type(4))) float  floatx4;  // MFMA acc

static __device__ __forceinline__ uint  asu(float f){ return __float_as_uint(f); }
static __device__ __forceinline__ float asf(uint u){ return __uint_as_float(u); }
static __device__ __forceinline__ ushort f2bf_rne(float f){
  uint u = asu(f); u += 0x7FFFu + ((u>>16)&1u); return (ushort)(u>>16);
}
static __device__ __forceinline__ float bf2f(ushort b){ return asf(((uint)b)<<16); }
// trunc-hi pack of two floats (a->lo16, b->hi16)
static __device__ __forceinline__ uint pack_hi(float a, float b){
  return (asu(a)>>16) | (asu(b)&0xFFFF0000u);
}
// trunc-bf16 of residuals after trunc-hi
static __device__ __forceinline__ uint pack_lo(float a, float b){
  float ra = a - asf(asu(a)&0xFFFF0000u);
  float rb = b - asf(asu(b)&0xFFFF0000u);
  return (asu(ra)>>16) | (asu(rb)&0xFFFF0000u);
}
static __device__ __forceinline__ float ftanh(float v){
  float e = __expf(2.0f*v);
  return 1.0f - 2.0f*__builtin_amdgcn_rcpf(1.0f + e);   // exact 0 at v=0
}

// K-slot -> logical dim: 0..49 = h0..h49, 50..57 = x0..x7, -1 = pad
static __device__ __forceinline__ int slot_dim(int k){
  if (k < 48) return k;            // h0..h47
  if (k < 56) return 50 + (k-48);  // x0..x7   (kg=2's entire Bh1 range)
  if (k < 58) return 48 + (k-56);  // h48,h49  (kg=3's first pair)
  return -1;                       // pad
}
// D-position (t4, m) -> K-slot kappa (producer lane == consumer lane)
static __device__ __forceinline__ int kappa_of(int t4, int m){
  return (t4 < 2) ? 8*(m>>2) + 4*t4 + (m&3)
                  : 32 + 8*(m>>2) + 4*(t4-2) + (m&3);
}

__global__ __launch_bounds__(64, 1) void rnn_regchain2(
    const float* __restrict__ x, const float* __restrict__ W_ih,
    const float* __restrict__ W_hh, const float* __restrict__ b_ih,
    const float* __restrict__ b_hh, const float* __restrict__ fc_W,
    const float* __restrict__ fc_b, float* __restrict__ out)
{
  const int lane = threadIdx.x;
  const int col  = lane & 15;     // batch (B col n, A row m)
  const int kg   = lane >> 4;     // 0..3
  const int b0   = blockIdx.x * 16;
  const bool isx = (kg == 2);     // this lane's Bh1/Bl1 slots carry x

  // ---- W fragments (A-operand), hi(rne)/lo(trunc-residual), in VGPRs ----
  short8 Wh[4][2], Wl[4][2];
#pragma unroll
  for (int t4 = 0; t4 < 4; ++t4) {
    const int dout = slot_dim(kappa_of(t4, col));     // output dim of A row m=col
    const bool real = (dout >= 0 && dout < H_DIM);
#pragma unroll
    for (int kh = 0; kh < 2; ++kh) {
      union { ushort u[8]; short8 v; } hu, lu;
#pragma unroll
      for (int j = 0; j < 8; ++j) {
        int din = slot_dim(kh*32 + kg*8 + j);
        float w = 0.f;
        if (real && din >= 0) {
          if (din < H_DIM) w = W_hh[dout*H_DIM + din];
          else             w = W_ih[dout*DIN + (din - H_DIM)];
        }
        ushort h = f2bf_rne(w);
        hu.u[j] = h;
        lu.u[j] = (ushort)(asu(w - bf2f(h)) >> 16);
      }
      Wh[t4][kh] = hu.v; Wl[t4][kh] = lu.v;
    }
  }

  // bias per acc reg (D row m = kg*4 + r); fake rows get 0 -> self-zeroing
  floatx4 bias[4];
#pragma unroll
  for (int t4 = 0; t4 < 4; ++t4)
#pragma unroll
    for (int r = 0; r < 4; ++r) {
      int d = slot_dim(kappa_of(t4, 4*kg + r));
      bias[t4][r] = (d >= 0 && d < H_DIM) ? (b_ih[d] + b_hh[d]) : 0.f;
    }

  // ---- x: lane kg=2 owns all 8 dims of its batch; 4-deep rotating prefetch
  const float4* xp4 = (const float4*)(x + (size_t)(b0 + col) * (T_LEN * DIN));
  float4 q0a={0,0,0,0}, q0b={0,0,0,0}, q1a={0,0,0,0}, q1b={0,0,0,0};
  float4 q2a={0,0,0,0}, q2b={0,0,0,0}, q3a={0,0,0,0}, q3b={0,0,0,0};
  float4 x0a={0,0,0,0}, x0b={0,0,0,0};
  if (isx) {
    x0a = xp4[0]; x0b = xp4[1];          // x_0
    q0a = xp4[2]; q0b = xp4[3];          // x_1
    q1a = xp4[4]; q1b = xp4[5];          // x_2
    q2a = xp4[6]; q2b = xp4[7];          // x_3
    q3a = xp4[8]; q3b = xp4[9];          // x_4
  }

  // ---- initial frags: h_0 = 0 everywhere; x_0 in kg=2's Bh1/Bl1 ----
  short8 Bh0, Bh1, Bl0, Bl1;
  {
    union { uint u[4]; short8 v; } z, xh, xl;
    z.u[0]=z.u[1]=z.u[2]=z.u[3]=0;
    xh.u[0] = isx ? pack_hi(x0a.x,x0a.y) : 0u;
    xh.u[1] = isx ? pack_hi(x0a.z,x0a.w) : 0u;
    xh.u[2] = isx ? pack_hi(x0b.x,x0b.y) : 0u;
    xh.u[3] = isx ? pack_hi(x0b.z,x0b.w) : 0u;
    xl.u[0] = isx ? pack_lo(x0a.x,x0a.y) : 0u;
    xl.u[1] = isx ? pack_lo(x0a.z,x0a.w) : 0u;
    xl.u[2] = isx ? pack_lo(x0b.x,x0b.y) : 0u;
    xl.u[3] = isx ? pack_lo(x0b.z,x0b.w) : 0u;
    Bh0 = z.v; Bl0 = z.v; Bh1 = xh.v; Bl1 = xl.v;
  }

  // ---- main loop: zero LDS, zero barriers, pure register recurrence ----
  auto phase = [&](float4& qa, float4& qb, int tload) {
    // 6-MFMA chain per tile, bias as C-init (no acc movs)
    floatx4 acc0 = __builtin_amdgcn_mfma_f32_16x16x32_bf16(Wh[0][0], Bh0, bias[0], 0,0,0);
    floatx4 acc1 = __builtin_amdgcn_mfma_f32_16x16x32_bf16(Wh[1][0], Bh0, bias[1], 0,0,0);
    floatx4 acc2 = __builtin_amdgcn_mfma_f32_16x16x32_bf16(Wh[2][0], Bh0, bias[2], 0,0,0);
    floatx4 acc3 = __builtin_amdgcn_mfma_f32_16x16x32_bf16(Wh[3][0], Bh0, bias[3], 0,0,0);
    acc0 = __builtin_amdgcn_mfma_f32_16x16x32_bf16(Wh[0][1], Bh1, acc0, 0,0,0);
    acc1 = __builtin_amdgcn_mfma_f32_16x16x32_bf16(Wh[1][1], Bh1, acc1, 0,0,0);
    acc2 = __builtin_amdgcn_mfma_f32_16x16x32_bf16(Wh[2][1], Bh1, acc2, 0,0,0);
    acc3 = __builtin_amdgcn_mfma_f32_16x16x32_bf16(Wh[3][1], Bh1, acc3, 0,0,0);
    acc0 = __builtin_amdgcn_mfma_f32_16x16x32_bf16(Wl[0][0], Bh0, acc0, 0,0,0);
    acc1 = __builtin_amdgcn_mfma_f32_16x16x32_bf16(Wl[1][0], Bh0, acc1, 0,0,0);
    acc2 = __builtin_amdgcn_mfma_f32_16x16x32_bf16(Wl[2][0], Bh0, acc2, 0,0,0);
    acc3 = __builtin_amdgcn_mfma_f32_16x16x32_bf16(Wl[3][0], Bh0, acc3, 0,0,0);
    acc0 = __builtin_amdgcn_mfma_f32_16x16x32_bf16(Wl[0][1], Bh1, acc0, 0,0,0);
    acc1 = __builtin_amdgcn_mfma_f32_16x16x32_bf16(Wl[1][1], Bh1, acc1, 0,0,0);
    acc2 = __builtin_amdgcn_mfma_f32_16x16x32_bf16(Wl[2][1], Bh1, acc2, 0,0,0);
    acc3 = __builtin_amdgcn_mfma_f32_16x16x32_bf16(Wl[3][1], Bh1, acc3, 0,0,0);
    acc0 = __builtin_amdgcn_mfma_f32_16x16x32_bf16(Wh[0][0], Bl0, acc0, 0,0,0);
    acc1 = __builtin_amdgcn_mfma_f32_16x16x32_bf16(Wh[1][0], Bl0, acc1, 0,0,0);
    acc2 = __builtin_amdgcn_mfma_f32_16x16x32_bf16(Wh[2][0], Bl0, acc2, 0,0,0);
    acc3 = __builtin_amdgcn_mfma_f32_16x16x32_bf16(Wh[3][0], Bl0, acc3, 0,0,0);
    acc0 = __builtin_amdgcn_mfma_f32_16x16x32_bf16(Wh[0][1], Bl1, acc0, 0,0,0);
    acc1 = __builtin_amdgcn_mfma_f32_16x16x32_bf16(Wh[1][1], Bl1, acc1, 0,0,0);
    acc2 = __builtin_amdgcn_mfma_f32_16x16x32_bf16(Wh[2][1], Bl1, acc2, 0,0,0);
    acc3 = __builtin_amdgcn_mfma_f32_16x16x32_bf16(Wh[3][1], Bl1, acc3, 0,0,0);

    // x packs for x_{t+1} (valid on kg=2; garbage elsewhere, selected away)
    uint xh0 = pack_hi(qa.x,qa.y), xh1 = pack_hi(qa.z,qa.w);
    uint xh2 = pack_hi(qb.x,qb.y), xh3 = pack_hi(qb.z,qb.w);
    uint xl0 = pack_lo(qa.x,qa.y), xl1 = pack_lo(qa.z,qa.w);
    uint xl2 = pack_lo(qb.x,qb.y), xl3 = pack_lo(qb.z,qb.w);

    // reload this set for t = tload (clamped; junk tail never consumed)
    int tc = (tload > T_LEN-1) ? (T_LEN-1) : tload;
    if (isx) { qa = xp4[2*tc]; qb = xp4[2*tc+1]; }

    // tanh
    float t00=ftanh(acc0[0]), t01=ftanh(acc0[1]), t02=ftanh(acc0[2]), t03=ftanh(acc0[3]);
    float t10=ftanh(acc1[0]), t11=ftanh(acc1[1]), t12=ftanh(acc1[2]), t13=ftanh(acc1[3]);
    float t20=ftanh(acc2[0]), t21=ftanh(acc2[1]), t22=ftanh(acc2[2]), t23=ftanh(acc2[3]);
    float t30=ftanh(acc3[0]), t31=ftanh(acc3[1]), t32=ftanh(acc3[2]), t33=ftanh(acc3[3]);

    // frag build: Bh0/Bl0 = direct copies; Bh1/Bl1 = cndmask(kg==2, x, P)
    union { uint u[4]; short8 v; } a, b, c, d;
    a.u[0]=pack_hi(t00,t01); a.u[1]=pack_hi(t02,t03);
    a.u[2]=pack_hi(t10,t11); a.u[3]=pack_hi(t12,t13);
    c.u[0]=pack_lo(t00,t01); c.u[1]=pack_lo(t02,t03);
    c.u[2]=pack_lo(t10,t11); c.u[3]=pack_lo(t12,t13);
    b.u[0]= isx ? xh0 : pack_hi(t20,t21);
    b.u[1]= isx ? xh1 : pack_hi(t22,t23);
    b.u[2]= isx ? xh2 : pack_hi(t30,t31);
    b.u[3]= isx ? xh3 : pack_hi(t32,t33);
    d.u[0]= isx ? xl0 : pack_lo(t20,t21);
    d.u[1]= isx ? xl1 : pack_lo(t22,t23);
    d.u[2]= isx ? xl2 : pack_lo(t30,t31);
    d.u[3]= isx ? xl3 : pack_lo(t32,t33);
    Bh0=a.v; Bl0=c.v; Bh1=b.v; Bl1=d.v;
  };

  for (int it = 0; it < T_LEN; it += 4) {
    phase(q0a, q0b, it + 5);
    phase(q1a, q1b, it + 6);
    phase(q2a, q2b, it + 7);
    phase(q3a, q3b, it + 8);
  }
  // frags now hold h_512 (hi in Bh0/Bh1, lo in Bl0/Bl1)

  // ---- fc readout ----
  union { uint u[4]; short8 v; } fh0, fh1, fl0, fl1;
  fh0.v=Bh0; fh1.v=Bh1; fl0.v=Bl0; fl1.v=Bl1;
  float fs = 0.f;
#pragma unroll
  for (int s = 0; s < 4; ++s) {        // Bh0: dims 8kg+2s, 8kg+2s+1 (all real)
    int dd = 8*kg + 2*s;
    fs += fc_W[dd]   * (bf2f((ushort)fh0.u[s])       + bf2f((ushort)fl0.u[s]));
    fs += fc_W[dd+1] * (bf2f((ushort)(fh0.u[s]>>16)) + bf2f((ushort)(fl0.u[s]>>16)));
  }
  if (kg < 2) {                        // Bh1: kg=0 -> 32..39, kg=1 -> 40..47
#pragma unroll
    for (int s = 0; s < 4; ++s) {
      int dd = 32 + 8*kg + 2*s;
      fs += fc_W[dd]   * (bf2f((ushort)fh1.u[s])       + bf2f((ushort)fl1.u[s]));
      fs += fc_W[dd+1] * (bf2f((ushort)(fh1.u[s]>>16)) + bf2f((ushort)(fl1.u[s]>>16)));
    }
  } else if (kg == 3) {                // slot0 -> dims 48,49
    fs += fc_W[48] * (bf2f((ushort)fh1.u[0])       + bf2f((ushort)fl1.u[0]));
    fs += fc_W[49] * (bf2f((ushort)(fh1.u[0]>>16)) + bf2f((ushort)(fl1.u[0]>>16)));
  }
  fs += __shfl_xor(fs, 16);
  fs += __shfl_xor(fs, 32);
  if (kg == 0) out[b0 + col] = fs + fc_b[0];
}

extern "C" void kernel_launch(void* const* d_in, const int* in_sizes, int n_in,
                              void* d_out, int out_size, void* d_ws, size_t ws_size,
                              hipStream_t stream) {
  const float* x    = (const float*)d_in[0];
  const float* W_ih = (const float*)d_in[1];
  const float* W_hh = (const float*)d_in[2];
  const float* b_ih = (const float*)d_in[3];
  const float* b_hh = (const float*)d_in[4];
  const float* fc_W = (const float*)d_in[5];
  const float* fc_b = (const float*)d_in[6];
  rnn_regchain2<<<dim3(B_TOT / 16), dim3(64), 0, stream>>>(
      x, W_ih, W_hh, b_ih, b_hh, fc_W, fc_b, (float*)d_out);
}